// Round 6
// baseline (244.114 us; speedup 1.0000x reference)
//
#include <hip/hip_runtime.h>
#include <hip/hip_bf16.h>

constexpr int S_ = 4096;
constexpr int D_ = 512;

using f32x4 = __attribute__((ext_vector_type(4))) float;
using s16x4 = __attribute__((ext_vector_type(4))) short;
using s16x8 = __attribute__((ext_vector_type(8))) short;
using u16x4 = __attribute__((ext_vector_type(4))) unsigned short;
using u16x8 = __attribute__((ext_vector_type(8))) unsigned short;

__device__ __forceinline__ unsigned short f2bf(float f) {
    union { float f; unsigned u; } v; v.f = f;
    unsigned r = v.u + 0x7FFFu + ((v.u >> 16) & 1u);
    return (unsigned short)(r >> 16);
}

__device__ __forceinline__ float bf2f(unsigned short u) {
    union { unsigned u; float f; } v; v.u = (unsigned)u << 16; return v.f;
}

__device__ __forceinline__ unsigned pack_bf16(float lo, float hi) {
    float2 t; t.x = lo; t.y = hi;
    __hip_bfloat162 b = __float22bfloat162_rn(t);
    union { __hip_bfloat162 b; unsigned u; } cv; cv.b = b; return cv.u;
}

__device__ __forceinline__ f32x4 mfma16(s16x4 a, s16x4 b, f32x4 c) {
#if __has_builtin(__builtin_amdgcn_mfma_f32_16x16x16bf16_1k)
    return __builtin_amdgcn_mfma_f32_16x16x16bf16_1k(a, b, c, 0, 0, 0);
#elif __has_builtin(__builtin_amdgcn_mfma_f32_16x16x16_bf16)
    return __builtin_amdgcn_mfma_f32_16x16x16_bf16(a, b, c, 0, 0, 0);
#else
    asm volatile("v_mfma_f32_16x16x16_bf16 %0, %1, %2, %0" : "+v"(c) : "v"(a), "v"(b));
    return c;
#endif
}

// Y[M=4096][N=512] = (X[M][512] @ W[N][512]^T) * scale
// OUT_MODE: 0 = bf16 row-major, 1 = bf16 transposed ([N][S_]), 2 = fp32 row-major
template<bool IN_BF16, int OUT_MODE>
__global__ __launch_bounds__(256) void proj_kernel(const void* __restrict__ Xv,
                                                   const float* __restrict__ W,
                                                   void* __restrict__ Yv, float scale) {
    constexpr int BM = 128, BN = 64, BK = 64;
    __shared__ unsigned short Xs[BM][BK + 8];
    __shared__ unsigned short Ws_[BN][BK + 8];
    const int m0 = blockIdx.x * BM;
    const int n0 = blockIdx.y * BN;
    const int tid = threadIdx.x;
    const int lane = tid & 63, w = tid >> 6;
    const int wi = w >> 1, wj = w & 1;
    const int lr = lane & 15, lg = lane >> 4;

    f32x4 acc[4][2] = {};

    for (int kt = 0; kt < D_ / BK; ++kt) {
        const int k0 = kt * BK;
        __syncthreads();
        if (IN_BF16) {
            const unsigned short* X = (const unsigned short*)Xv;
#pragma unroll
            for (int r = 0; r < 4; ++r) {
                int idx = tid + r * 256;
                int row = idx >> 3, c8 = idx & 7;
                u16x8 vv = *(const u16x8*)(X + (size_t)(m0 + row) * D_ + k0 + c8 * 8);
                *(u16x8*)&Xs[row][c8 * 8] = vv;
            }
        } else {
            const float* X = (const float*)Xv;
#pragma unroll
            for (int r = 0; r < 8; ++r) {
                int idx = tid + r * 256;
                int row = idx >> 4, c4 = idx & 15;
                f32x4 vv = *(const f32x4*)(X + (size_t)(m0 + row) * D_ + k0 + c4 * 4);
                u16x4 o;
#pragma unroll
                for (int t = 0; t < 4; ++t) o[t] = f2bf(vv[t]);
                *(u16x4*)&Xs[row][c4 * 4] = o;
            }
        }
#pragma unroll
        for (int r = 0; r < 4; ++r) {
            int idx = tid + r * 256;
            int row = idx >> 4, c4 = idx & 15;
            f32x4 vv = *(const f32x4*)(W + (size_t)(n0 + row) * D_ + k0 + c4 * 4);
            u16x4 o;
#pragma unroll
            for (int t = 0; t < 4; ++t) o[t] = f2bf(vv[t]);
            *(u16x4*)&Ws_[row][c4 * 4] = o;
        }
        __syncthreads();
#pragma unroll
        for (int ks = 0; ks < 2; ++ks) {
            s16x8 a[4], b[2];
#pragma unroll
            for (int mf = 0; mf < 4; ++mf)
                a[mf] = *(const s16x8*)&Xs[wi * 64 + mf * 16 + lr][ks * 32 + lg * 8];
#pragma unroll
            for (int nf = 0; nf < 2; ++nf)
                b[nf] = *(const s16x8*)&Ws_[wj * 32 + nf * 16 + lr][ks * 32 + lg * 8];
#pragma unroll
            for (int mf = 0; mf < 4; ++mf)
#pragma unroll
                for (int nf = 0; nf < 2; ++nf)
                    acc[mf][nf] = __builtin_amdgcn_mfma_f32_16x16x32_bf16(a[mf], b[nf], acc[mf][nf], 0, 0, 0);
        }
    }

    if (OUT_MODE == 1) {
        __syncthreads();
        unsigned short* T = &Xs[0][0] + w * 2304;   // per-wave [32][72]
#pragma unroll
        for (int mf = 0; mf < 4; ++mf)
#pragma unroll
            for (int nf = 0; nf < 2; ++nf)
#pragma unroll
                for (int r = 0; r < 4; ++r) {
                    int n_loc = nf * 16 + lr;
                    int i_loc = mf * 16 + lg * 4 + r;
                    T[n_loc * 72 + i_loc] = f2bf(acc[mf][nf][r] * scale);
                }
        __syncthreads();
        unsigned short* Y = (unsigned short*)Yv;
#pragma unroll
        for (int rr = 0; rr < 4; ++rr) {
            int chunk = lane + rr * 64;
            int n_loc = chunk >> 3, c8 = chunk & 7;
            u16x8 vv = *(const u16x8*)&T[n_loc * 72 + c8 * 8];
            *(u16x8*)(Y + (size_t)(n0 + wj * 32 + n_loc) * S_ + m0 + wi * 64 + c8 * 8) = vv;
        }
    } else {
#pragma unroll
        for (int mf = 0; mf < 4; ++mf)
#pragma unroll
            for (int nf = 0; nf < 2; ++nf)
#pragma unroll
                for (int r = 0; r < 4; ++r) {
                    int i = m0 + wi * 64 + mf * 16 + lg * 4 + r;
                    int n = n0 + wj * 32 + nf * 16 + lr;
                    float val = acc[mf][nf][r] * scale;
                    if (OUT_MODE == 0) ((unsigned short*)Yv)[(size_t)i * D_ + n] = f2bf(val);
                    else                ((float*)Yv)[(size_t)i * D_ + n] = val;
                }
    }
}

// Attention, head-axis softmax, barrier-light.
// Block = 4 waves = one team of 32 q-rows. Wave w owns heads 2w,2w+1 (k-slice
// kb=w*128). Swapped QK (mfma(K,Q)): lane holds S[j][i] -> softmax lane-local
// except the 8-head denominator, exchanged via LDS + raw lgkm-only barrier
// (vmem loads stay in flight). P fragment == B-operand of 16x16x16 PV MFMA
// directly. Output O[i][d] partial (bf16) to partial[jc][S][D].
// K loads issued BEFORE V loads: QK waits only on K; V lands during softmax.
__global__ __launch_bounds__(256, 2) void attn_kernel(const unsigned short* __restrict__ Qp,
                                                      const unsigned short* __restrict__ Kp,
                                                      const unsigned short* __restrict__ VpT,
                                                      unsigned short* __restrict__ partial,
                                                      int tpc) {
    __shared__ float den[2][4][2][64][4];          // [slot][wave][ifrag][lane][r] = 16 KB
    const int nblk = gridDim.x;
    const int cpx = nblk >> 3;
    const int bid = blockIdx.x;
    const int rank = (bid & 7) * cpx + (bid >> 3); // XCD-contiguous (njc=8: XCD == jc)
    const int jc = rank >> 7;
    const int i0 = (rank & 127) * 32;
    const int tid = threadIdx.x;
    const int lane = tid & 63, w = tid >> 6;
    const int lr = lane & 15, lg = lane >> 4;
    const int kb = w * 128;                        // this wave's k-slice (heads 2w,2w+1)

    // Q fragments for the whole k-slice: [ifrag][kfrag], persistent registers
    s16x8 q[2][4];
#pragma unroll
    for (int f = 0; f < 2; ++f)
#pragma unroll
        for (int kf = 0; kf < 4; ++kf)
            q[f][kf] = *(const s16x8*)(Qp + (size_t)(i0 + f * 16 + lr) * D_ + kb + kf * 32 + lg * 8);

    f32x4 acc[8][2] = {};                          // [dfrag][ifrag]

    const int t0 = jc * tpc;
    const int t1 = t0 + tpc;

    for (int t = t0; t < t1; ++t) {
        const int j0 = t * 16;
        const int slot = t & 1;

        // ---- K fragments first (QK consumer waits only on these) ----
        s16x8 kA[4];
#pragma unroll
        for (int kf = 0; kf < 4; ++kf)
            kA[kf] = *(const s16x8*)(Kp + (size_t)(j0 + lr) * D_ + kb + kf * 32 + lg * 8);
        // ---- V fragments second: stay in flight through softmax ----
        s16x4 vA[8];
#pragma unroll
        for (int df = 0; df < 8; ++df)
            vA[df] = *(const s16x4*)(VpT + (size_t)(kb + df * 16 + lr) * S_ + j0 + lg * 4);

        // ---- QK^T (swapped): sf[hh][f] = S[h=2w+hh][j=lg*4+r][i=f*16+lr] ----
        f32x4 sf[2][2] = {};
        __builtin_amdgcn_s_setprio(1);
#pragma unroll
        for (int hh = 0; hh < 2; ++hh)
#pragma unroll
            for (int ks = 0; ks < 2; ++ks)
#pragma unroll
                for (int f = 0; f < 2; ++f)
                    sf[hh][f] = __builtin_amdgcn_mfma_f32_16x16x32_bf16(kA[hh * 2 + ks], q[f][hh * 2 + ks], sf[hh][f], 0, 0, 0);
        __builtin_amdgcn_s_setprio(0);

        // ---- exp2 (Q pre-scaled by 1/8*log2e) + local 2-head denominator ----
#pragma unroll
        for (int hh = 0; hh < 2; ++hh)
#pragma unroll
            for (int f = 0; f < 2; ++f)
#pragma unroll
                for (int r = 0; r < 4; ++r)
                    sf[hh][f][r] = exp2f(sf[hh][f][r]);
#pragma unroll
        for (int f = 0; f < 2; ++f)
            *(f32x4*)den[slot][w][f][lane] = sf[0][f] + sf[1][f];

        // raw barrier: LDS-only drain, vmem (V prefetch) stays in flight
        asm volatile("s_waitcnt lgkmcnt(0)\n\ts_barrier" ::: "memory");

        // ---- total denominator over all 4 waves (8 heads) ----
        f32x4 dt[2];
#pragma unroll
        for (int f = 0; f < 2; ++f) {
            dt[f] = *(const f32x4*)den[slot][0][f][lane];
#pragma unroll
            for (int wp = 1; wp < 4; ++wp)
                dt[f] += *(const f32x4*)den[slot][wp][f][lane];
        }

        // ---- normalize + pack: P fragment is directly the 16x16x16 B operand ----
        s16x4 pb[2][2];
#pragma unroll
        for (int f = 0; f < 2; ++f) {
            f32x4 rd;
#pragma unroll
            for (int r = 0; r < 4; ++r) rd[r] = __builtin_amdgcn_rcpf(dt[f][r]);
#pragma unroll
            for (int hh = 0; hh < 2; ++hh) {
                union { s16x4 v; uint2 u; } pc;
                pc.u.x = pack_bf16(sf[hh][f][0] * rd[0], sf[hh][f][1] * rd[1]);
                pc.u.y = pack_bf16(sf[hh][f][2] * rd[2], sf[hh][f][3] * rd[3]);
                pb[hh][f] = pc.v;
            }
        }

        // ---- PV: acc[df][f] += V^T[d][j16] * P[i][j16] ----
        __builtin_amdgcn_s_setprio(1);
#pragma unroll
        for (int df = 0; df < 8; ++df)
#pragma unroll
            for (int f = 0; f < 2; ++f)
                acc[df][f] = mfma16(vA[df], pb[df >> 2][f], acc[df][f]);
        __builtin_amdgcn_s_setprio(0);
    }

    // ---- store O[i][d] partial, bf16, coalesced u16x4 per lane ----
    unsigned short* P = partial + (size_t)jc * S_ * D_;
#pragma unroll
    for (int df = 0; df < 8; ++df)
#pragma unroll
        for (int f = 0; f < 2; ++f) {
            union { u16x4 v; uint2 u; } pc;
            pc.u.x = pack_bf16(acc[df][f][0], acc[df][f][1]);
            pc.u.y = pack_bf16(acc[df][f][2], acc[df][f][3]);
            *(u16x4*)(P + (size_t)(i0 + f * 16 + lr) * D_ + kb + df * 16 + lg * 4) = pc.v;
        }
}

// Sum njc bf16 partials -> bf16 ao. Memory-bound streaming sum.
__global__ __launch_bounds__(256) void reduceN_kernel(const unsigned short* __restrict__ partial,
                                                      unsigned short* __restrict__ outp, int njc) {
    size_t base = ((size_t)blockIdx.x * 256 + threadIdx.x) * 8;
    float s[8] = {};
    for (int c = 0; c < njc; ++c) {
        u16x8 vv = *(const u16x8*)(partial + (size_t)c * S_ * D_ + base);
#pragma unroll
        for (int e = 0; e < 8; ++e) s[e] += bf2f(vv[e]);
    }
    u16x8 o;
#pragma unroll
    for (int e = 0; e < 8; ++e) o[e] = f2bf(s[e]);
    *(u16x8*)(outp + base) = o;
}

extern "C" void kernel_launch(void* const* d_in, const int* in_sizes, int n_in,
                              void* d_out, int out_size, void* d_ws, size_t ws_size,
                              hipStream_t stream) {
    const float* q  = (const float*)d_in[0];
    const float* k  = (const float*)d_in[1];
    const float* v  = (const float*)d_in[2];
    const float* Wq = (const float*)d_in[3];
    const float* Wk = (const float*)d_in[4];
    const float* Wv = (const float*)d_in[5];
    const float* Wo = (const float*)d_in[6];

    // ws: 12MB (Qp,Kp,VpT) + njc*4MB (bf16 partial) + 4MB (ao)
    int njc = 2;
    if      (ws_size >= ((size_t)(16 + 4 * 8) << 20)) njc = 8;   // 1024 blocks = 4/CU
    else if (ws_size >= ((size_t)(16 + 4 * 4) << 20)) njc = 4;

    char* ws = (char*)d_ws;
    unsigned short* Qp  = (unsigned short*)(ws);                    // 4 MB bf16 [S][D]
    unsigned short* Kp  = (unsigned short*)(ws + (4u  << 20));      // 4 MB bf16 [S][D]
    unsigned short* VpT = (unsigned short*)(ws + (8u  << 20));      // 4 MB bf16 [D][S]
    unsigned short* part= (unsigned short*)(ws + (12u << 20));      // njc * 4 MB bf16 [jc][S][D]
    unsigned short* ao  = (unsigned short*)(ws + ((size_t)(12 + 4 * njc) << 20)); // 4 MB bf16

    const float qscale = 0.125f * 1.44269504088896340736f;  // 1/8 * log2(e)

    dim3 pb(256);
    dim3 pg(S_ / 128, D_ / 64);
    proj_kernel<false, 0><<<pg, pb, 0, stream>>>(q, Wq, Qp, qscale);
    proj_kernel<false, 0><<<pg, pb, 0, stream>>>(k, Wk, Kp, 1.0f);
    proj_kernel<false, 1><<<pg, pb, 0, stream>>>(v, Wv, VpT, 1.0f);
    attn_kernel<<<dim3(128 * njc), pb, 0, stream>>>(Qp, Kp, VpT, part, S_ / 16 / njc);
    reduceN_kernel<<<dim3(S_ * D_ / 2048), pb, 0, stream>>>(part, ao, njc);
    proj_kernel<true, 2><<<pg, pb, 0, stream>>>(ao, Wo, (float*)d_out, 1.0f);
}

// Round 8
// 241.041 us; speedup vs baseline: 1.0127x; 1.0127x over previous
//
#include <hip/hip_runtime.h>
#include <hip/hip_bf16.h>

constexpr int S_ = 4096;
constexpr int D_ = 512;

using f32x4 = __attribute__((ext_vector_type(4))) float;
using s16x4 = __attribute__((ext_vector_type(4))) short;
using s16x8 = __attribute__((ext_vector_type(8))) short;
using u16x4 = __attribute__((ext_vector_type(4))) unsigned short;
using u16x8 = __attribute__((ext_vector_type(8))) unsigned short;

__device__ __forceinline__ unsigned short f2bf(float f) {
    union { float f; unsigned u; } v; v.f = f;
    unsigned r = v.u + 0x7FFFu + ((v.u >> 16) & 1u);
    return (unsigned short)(r >> 16);
}

__device__ __forceinline__ float bf2f(unsigned short u) {
    union { unsigned u; float f; } v; v.u = (unsigned)u << 16; return v.f;
}

__device__ __forceinline__ unsigned pack_bf16(float lo, float hi) {
    float2 t; t.x = lo; t.y = hi;
    __hip_bfloat162 b = __float22bfloat162_rn(t);
    union { __hip_bfloat162 b; unsigned u; } cv; cv.b = b; return cv.u;
}

__device__ __forceinline__ float fexp2(float x) {
    return exp2f(x);   // lowers to v_exp_f32 with -O3 fast path on gfx950
}

// 16x16x16 bf16 MFMA via inline asm (no builtin exposed on gfx950; HW op exists,
// verified working in rounds 5-6).
__device__ __forceinline__ f32x4 mfma16(s16x4 a, s16x4 b, f32x4 c) {
    asm volatile("v_mfma_f32_16x16x16_bf16 %0, %1, %2, %0" : "+v"(c) : "v"(a), "v"(b));
    return c;
}

// Y[M=4096][N=512] = (X[M][512] @ W[N][512]^T) * scale
// OUT_MODE: 0 = bf16 row-major, 1 = bf16 transposed ([N][S_]), 2 = fp32 row-major
template<bool IN_BF16, int OUT_MODE>
__global__ __launch_bounds__(256) void proj_kernel(const void* __restrict__ Xv,
                                                   const float* __restrict__ W,
                                                   void* __restrict__ Yv, float scale) {
    constexpr int BM = 128, BN = 64, BK = 64;
    __shared__ unsigned short Xs[BM][BK + 8];
    __shared__ unsigned short Ws_[BN][BK + 8];
    const int m0 = blockIdx.x * BM;
    const int n0 = blockIdx.y * BN;
    const int tid = threadIdx.x;
    const int lane = tid & 63, w = tid >> 6;
    const int wi = w >> 1, wj = w & 1;
    const int lr = lane & 15, lg = lane >> 4;

    f32x4 acc[4][2] = {};

    for (int kt = 0; kt < D_ / BK; ++kt) {
        const int k0 = kt * BK;
        __syncthreads();
        if (IN_BF16) {
            const unsigned short* X = (const unsigned short*)Xv;
#pragma unroll
            for (int r = 0; r < 4; ++r) {
                int idx = tid + r * 256;
                int row = idx >> 3, c8 = idx & 7;
                u16x8 vv = *(const u16x8*)(X + (size_t)(m0 + row) * D_ + k0 + c8 * 8);
                *(u16x8*)&Xs[row][c8 * 8] = vv;
            }
        } else {
            const float* X = (const float*)Xv;
#pragma unroll
            for (int r = 0; r < 8; ++r) {
                int idx = tid + r * 256;
                int row = idx >> 4, c4 = idx & 15;
                f32x4 vv = *(const f32x4*)(X + (size_t)(m0 + row) * D_ + k0 + c4 * 4);
                u16x4 o;
#pragma unroll
                for (int t = 0; t < 4; ++t) o[t] = f2bf(vv[t]);
                *(u16x4*)&Xs[row][c4 * 4] = o;
            }
        }
#pragma unroll
        for (int r = 0; r < 4; ++r) {
            int idx = tid + r * 256;
            int row = idx >> 4, c4 = idx & 15;
            f32x4 vv = *(const f32x4*)(W + (size_t)(n0 + row) * D_ + k0 + c4 * 4);
            u16x4 o;
#pragma unroll
            for (int t = 0; t < 4; ++t) o[t] = f2bf(vv[t]);
            *(u16x4*)&Ws_[row][c4 * 4] = o;
        }
        __syncthreads();
#pragma unroll
        for (int ks = 0; ks < 2; ++ks) {
            s16x8 a[4], b[2];
#pragma unroll
            for (int mf = 0; mf < 4; ++mf)
                a[mf] = *(const s16x8*)&Xs[wi * 64 + mf * 16 + lr][ks * 32 + lg * 8];
#pragma unroll
            for (int nf = 0; nf < 2; ++nf)
                b[nf] = *(const s16x8*)&Ws_[wj * 32 + nf * 16 + lr][ks * 32 + lg * 8];
#pragma unroll
            for (int mf = 0; mf < 4; ++mf)
#pragma unroll
                for (int nf = 0; nf < 2; ++nf)
                    acc[mf][nf] = __builtin_amdgcn_mfma_f32_16x16x32_bf16(a[mf], b[nf], acc[mf][nf], 0, 0, 0);
        }
    }

    if (OUT_MODE == 1) {
        __syncthreads();
        unsigned short* T = &Xs[0][0] + w * 2304;   // per-wave [32][72]
#pragma unroll
        for (int mf = 0; mf < 4; ++mf)
#pragma unroll
            for (int nf = 0; nf < 2; ++nf)
#pragma unroll
                for (int r = 0; r < 4; ++r) {
                    int n_loc = nf * 16 + lr;
                    int i_loc = mf * 16 + lg * 4 + r;
                    T[n_loc * 72 + i_loc] = f2bf(acc[mf][nf][r] * scale);
                }
        __syncthreads();
        unsigned short* Y = (unsigned short*)Yv;
#pragma unroll
        for (int rr = 0; rr < 4; ++rr) {
            int chunk = lane + rr * 64;
            int n_loc = chunk >> 3, c8 = chunk & 7;
            u16x8 vv = *(const u16x8*)&T[n_loc * 72 + c8 * 8];
            *(u16x8*)(Y + (size_t)(n0 + wj * 32 + n_loc) * S_ + m0 + wi * 64 + c8 * 8) = vv;
        }
    } else {
#pragma unroll
        for (int mf = 0; mf < 4; ++mf)
#pragma unroll
            for (int nf = 0; nf < 2; ++nf)
#pragma unroll
                for (int r = 0; r < 4; ++r) {
                    int i = m0 + wi * 64 + mf * 16 + lg * 4 + r;
                    int n = n0 + wj * 32 + nf * 16 + lr;
                    float val = acc[mf][nf][r] * scale;
                    if (OUT_MODE == 0) ((unsigned short*)Yv)[(size_t)i * D_ + n] = f2bf(val);
                    else                ((float*)Yv)[(size_t)i * D_ + n] = val;
                }
    }
}

// Attention, head-axis softmax. Block = 8 waves (512 thr) = one team of 32
// q-rows; wave w owns head w (k-slice kb=w*64). Swapped QK (mfma(K,Q)) ->
// lane-local exp; 8-head denominator exchanged via slot-dbuf LDS + raw
// lgkm-only barrier. K register double-buffered (prefetch t+1 during t);
// V issued oldest-first so counted vmcnt never drains the K prefetch.
// P fragment == B operand of 16x16x16 PV MFMA (no P LDS roundtrip).
__global__ __launch_bounds__(512, 4) void attn_kernel(const unsigned short* __restrict__ Qp,
                                                      const unsigned short* __restrict__ Kp,
                                                      const unsigned short* __restrict__ VpT,
                                                      unsigned short* __restrict__ partial,
                                                      int tpc) {
    __shared__ float den[2][8][2][64][4];          // [slot][wave][ifrag][lane][r] = 32 KB
    const int nblk = gridDim.x;
    const int cpx = nblk >> 3;
    const int bid = blockIdx.x;
    const int rank = (bid & 7) * cpx + (bid >> 3); // XCD-contiguous (njc=8: XCD == jc)
    const int jc = rank >> 7;
    const int i0 = (rank & 127) * 32;
    const int tid = threadIdx.x;
    const int lane = tid & 63, w = tid >> 6;       // w = head index
    const int lr = lane & 15, lg = lane >> 4;
    const int kb = w * 64;                         // this wave's k-slice (head w)

    // ---- per-lane constant element offsets (hoisted out of the loop) ----
    const int koff = lr * D_ + kb + lg * 8;        // K row offset within j-tile
    int voff[4];
#pragma unroll
    for (int df = 0; df < 4; ++df)
        voff[df] = (kb + df * 16 + lr) * S_ + lg * 4;

    // ---- persistent Q fragments: head w's 64 k-cols for 32 i-rows ----
    s16x8 q[2][2];
#pragma unroll
    for (int f = 0; f < 2; ++f)
#pragma unroll
        for (int kf = 0; kf < 2; ++kf)
            q[f][kf] = *(const s16x8*)(Qp + (size_t)(i0 + f * 16 + lr) * D_ + kb + kf * 32 + lg * 8);

    f32x4 acc[4][2] = {};                          // [dfrag][ifrag]

    const int t0 = jc * tpc;
    const int t1 = t0 + tpc;

    // K double-buffers
    s16x8 kA[2], kB[2];
    {
        const unsigned short* kbase = Kp + (size_t)t0 * 16 * D_;
        kA[0] = *(const s16x8*)(kbase + koff);
        kA[1] = *(const s16x8*)(kbase + koff + 32);
    }

    auto step = [&](int t, int slot, s16x8 (&kc)[2], s16x8 (&kn)[2]) {
        const int j0 = t * 16;
        // ---- V loads first (oldest; consumed this iter after barrier) ----
        const unsigned short* vb = VpT + j0;
        s16x4 vA[4];
#pragma unroll
        for (int df = 0; df < 4; ++df)
            vA[df] = *(const s16x4*)(vb + voff[df]);
        __builtin_amdgcn_sched_barrier(0);
        // ---- K prefetch for t+1 (stays in flight across this whole iter) ----
        const unsigned short* kbase = Kp + (size_t)(j0 + 16) * D_;
        kn[0] = *(const s16x8*)(kbase + koff);
        kn[1] = *(const s16x8*)(kbase + koff + 32);
        __builtin_amdgcn_sched_barrier(0);

        // ---- QK^T (swapped): sf[f] = S[h=w][j=lg*4+r][i=f*16+lr] ----
        f32x4 sf[2];
        __builtin_amdgcn_s_setprio(1);
#pragma unroll
        for (int f = 0; f < 2; ++f) {
            f32x4 s = {0.f, 0.f, 0.f, 0.f};
            s = __builtin_amdgcn_mfma_f32_16x16x32_bf16(kc[0], q[f][0], s, 0, 0, 0);
            s = __builtin_amdgcn_mfma_f32_16x16x32_bf16(kc[1], q[f][1], s, 0, 0, 0);
            sf[f] = s;
        }
        __builtin_amdgcn_s_setprio(0);

        // ---- exp2 (Q pre-scaled by 1/8*log2e); this head's denominator ----
#pragma unroll
        for (int f = 0; f < 2; ++f) {
#pragma unroll
            for (int r = 0; r < 4; ++r)
                sf[f][r] = fexp2(sf[f][r]);
            *(f32x4*)den[slot][w][f][lane] = sf[f];
        }

        // raw barrier: LDS drain only; vmem (K prefetch) stays in flight
        asm volatile("s_waitcnt lgkmcnt(0)" ::: "memory");
        __builtin_amdgcn_s_barrier();

        // ---- total denominator over 8 heads ----
        f32x4 dt[2];
#pragma unroll
        for (int f = 0; f < 2; ++f) {
            dt[f] = *(const f32x4*)den[slot][0][f][lane];
#pragma unroll
            for (int wp = 1; wp < 8; ++wp)
                dt[f] += *(const f32x4*)den[slot][wp][f][lane];
        }

        // ---- normalize + pack: P fragment is the 16x16x16 B operand ----
        s16x4 pb[2];
#pragma unroll
        for (int f = 0; f < 2; ++f) {
            f32x4 rd;
#pragma unroll
            for (int r = 0; r < 4; ++r) rd[r] = __builtin_amdgcn_rcpf(dt[f][r]);
            union { s16x4 v; uint2 u; } pc;
            pc.u.x = pack_bf16(sf[f][0] * rd[0], sf[f][1] * rd[1]);
            pc.u.y = pack_bf16(sf[f][2] * rd[2], sf[f][3] * rd[3]);
            pb[f] = pc.v;
        }

        // ---- PV: acc[df][f] += V^T[d][j16] * P[i][j16] ----
        __builtin_amdgcn_s_setprio(1);
#pragma unroll
        for (int df = 0; df < 4; ++df)
#pragma unroll
            for (int f = 0; f < 2; ++f)
                acc[df][f] = mfma16(vA[df], pb[f], acc[df][f]);
        __builtin_amdgcn_s_setprio(0);
    };

    for (int tt = t0; tt < t1; tt += 2) {          // tpc even: pairs complete
        step(tt,     0, kA, kB);
        step(tt + 1, 1, kB, kA);
    }

    // ---- store O[i][d] partial, bf16, coalesced u16x4 per lane ----
    unsigned short* P = partial + (size_t)jc * S_ * D_;
#pragma unroll
    for (int df = 0; df < 4; ++df)
#pragma unroll
        for (int f = 0; f < 2; ++f) {
            union { u16x4 v; uint2 u; } pc;
            pc.u.x = pack_bf16(acc[df][f][0], acc[df][f][1]);
            pc.u.y = pack_bf16(acc[df][f][2], acc[df][f][3]);
            *(u16x4*)(P + (size_t)(i0 + f * 16 + lr) * D_ + kb + df * 16 + lg * 4) = pc.v;
        }
}

// Sum njc bf16 partials -> bf16 ao. Memory-bound streaming sum.
__global__ __launch_bounds__(256) void reduceN_kernel(const unsigned short* __restrict__ partial,
                                                      unsigned short* __restrict__ outp, int njc) {
    size_t base = ((size_t)blockIdx.x * 256 + threadIdx.x) * 8;
    float s[8] = {};
    for (int c = 0; c < njc; ++c) {
        u16x8 vv = *(const u16x8*)(partial + (size_t)c * S_ * D_ + base);
#pragma unroll
        for (int e = 0; e < 8; ++e) s[e] += bf2f(vv[e]);
    }
    u16x8 o;
#pragma unroll
    for (int e = 0; e < 8; ++e) o[e] = f2bf(s[e]);
    *(u16x8*)(outp + base) = o;
}

extern "C" void kernel_launch(void* const* d_in, const int* in_sizes, int n_in,
                              void* d_out, int out_size, void* d_ws, size_t ws_size,
                              hipStream_t stream) {
    const float* q  = (const float*)d_in[0];
    const float* k  = (const float*)d_in[1];
    const float* v  = (const float*)d_in[2];
    const float* Wq = (const float*)d_in[3];
    const float* Wk = (const float*)d_in[4];
    const float* Wv = (const float*)d_in[5];
    const float* Wo = (const float*)d_in[6];

    // ws: 12MB (Qp,Kp,VpT) + njc*4MB (bf16 partial) + 4MB (ao)
    int njc = 2;
    if      (ws_size >= ((size_t)(16 + 4 * 8) << 20)) njc = 8;   // XCD == j-chunk
    else if (ws_size >= ((size_t)(16 + 4 * 4) << 20)) njc = 4;

    char* ws = (char*)d_ws;
    unsigned short* Qp  = (unsigned short*)(ws);                    // 4 MB bf16 [S][D]
    unsigned short* Kp  = (unsigned short*)(ws + (4u  << 20));      // 4 MB bf16 [S][D]
    unsigned short* VpT = (unsigned short*)(ws + (8u  << 20));      // 4 MB bf16 [D][S]
    unsigned short* part= (unsigned short*)(ws + (12u << 20));      // njc * 4 MB bf16 [jc][S][D]
    unsigned short* ao  = (unsigned short*)(ws + ((size_t)(12 + 4 * njc) << 20)); // 4 MB bf16

    const float qscale = 0.125f * 1.44269504088896340736f;  // 1/8 * log2(e)

    dim3 pb(256);
    dim3 pg(S_ / 128, D_ / 64);
    proj_kernel<false, 0><<<pg, pb, 0, stream>>>(q, Wq, Qp, qscale);
    proj_kernel<false, 0><<<pg, pb, 0, stream>>>(k, Wk, Kp, 1.0f);
    proj_kernel<false, 1><<<pg, pb, 0, stream>>>(v, Wv, VpT, 1.0f);
    attn_kernel<<<dim3(128 * njc), dim3(512), 0, stream>>>(Qp, Kp, VpT, part, S_ / 16 / njc);
    reduceN_kernel<<<dim3(S_ * D_ / 2048), pb, 0, stream>>>(part, ao, njc);
    proj_kernel<true, 2><<<pg, pb, 0, stream>>>(ao, Wo, (float*)d_out, 1.0f);
}